// Round 2
// baseline (24.625 us; speedup 1.0000x reference)
//
#include <hip/hip_runtime.h>

// out = 2x2 stride-2 max-pool of x (the reference's relu algebra collapses to
// max(a,b,c,d) per window).
// x: (32, 64, 112, 112) f32  ->  out: (32, 64, 56, 56) f32
//
// R1 change: each thread now owns ONE input float4 per row (2 output pixels,
// float2 store) instead of an output float4. Every load instruction is
// lane-contiguous (16 B/lane), every store is lane-contiguous (8 B/lane) --
// no 32 B lane stride, no reliance on L1 to merge half-used lines.

__global__ __launch_bounds__(256) void maxpool2x2_kernel(const float* __restrict__ x,
                                                         float* __restrict__ out,
                                                         int n_v2) {
    int t = blockIdx.x * blockDim.x + threadIdx.x;
    if (t >= n_v2) return;

    const int OW2 = 28;                 // 56 output cols / 2 per thread
    int row = t / OW2;                  // img*56 + oh
    int q   = t - row * OW2;            // which input float4 within the row
    int img = row / 56;                 // img = n*64 + c
    int oh  = row - img * 56;

    const float* base = x + (size_t)img * (112 * 112) + (size_t)(2 * oh) * 112 + q * 4;

    float4 r0 = *reinterpret_cast<const float4*>(base);        // row 2*oh
    float4 r1 = *reinterpret_cast<const float4*>(base + 112);  // row 2*oh+1

    float2 o;
    o.x = fmaxf(fmaxf(r0.x, r0.y), fmaxf(r1.x, r1.y));
    o.y = fmaxf(fmaxf(r0.z, r0.w), fmaxf(r1.z, r1.w));

    *reinterpret_cast<float2*>(out + (size_t)t * 2) = o;
}

extern "C" void kernel_launch(void* const* d_in, const int* in_sizes, int n_in,
                              void* d_out, int out_size, void* d_ws, size_t ws_size,
                              hipStream_t stream) {
    const float* x = (const float*)d_in[0];
    float* out = (float*)d_out;

    // out_size = 32*64*56*56 = 6,422,528 ; n_v2 = out_size/2 = 3,211,264
    int n_v2 = out_size / 2;
    int block = 256;
    int grid = (n_v2 + block - 1) / block;   // 12544

    maxpool2x2_kernel<<<grid, block, 0, stream>>>(x, out, n_v2);
}